// Round 8
// baseline (133.425 us; speedup 1.0000x reference)
//
#include <hip/hip_runtime.h>
#include <math.h>

// QGRUCell — Round 14: fuse A-conversion into the GEMM kernel.
// R13 A/B showed occupancy is not the limiter (16 vs 8 waves/CU: 43.0 vs
// 44.9us); 8 structures pin qgru at 43-50us. Remaining controllable cost is
// the cvt pre-pass (~10-14us, 92% of it A-conversion). This round: qgru
// stages A directly from f32 x/hid (2 coalesced float4 loads + 8 cvts +
// 2 ds_write_b64 per wave-step) into the SAME chunk layout as ws, so frag
// reads and numerics are bit-identical. W keeps the dma16/ws path (reused
// by 128 m-blocks). cvt shrinks to W-only: 192 blocks (~2us).
// Safety: same syncthreads-drain invariant as R7/R13 (compiler emits
// s_waitcnt vmcnt(0) lgkmcnt(0) before s_barrier).
// ws W layout unchanged: 512-f16 chunks at WCH0+(g*16+N32)*32+K16;
// chunk pos(row,k)=(k>>3&1)*256+row*8+(k&7).

typedef _Float16 f16x8  __attribute__((ext_vector_type(8)));
typedef _Float16 f16x4  __attribute__((ext_vector_type(4)));
typedef __bf16   bf16x8 __attribute__((ext_vector_type(8)));
typedef float    f32x16 __attribute__((ext_vector_type(16)));

namespace {

constexpr int Bsz = 8192, Ksz = 512, Hsz = 512;
constexpr int BM = 64, BN = 64;

constexpr unsigned WCH0    = 16384u;
constexpr unsigned NCHUNK  = 16384u + 3072u;          // 19456
constexpr unsigned WS_F16  = NCHUNK * 512u;           // 9,961,472 f16
constexpr size_t   WS_NEED = (size_t)WS_F16 * 2;      // 19,922,944 B

__device__ __forceinline__ float qround(float x, float s, float invs) {
    return floorf(x * s + 0.5f) * invs;
}

__device__ __forceinline__ float qsigmoid_dev(float x) {
    float iq = floorf(x * 134217728.0f + 0.5f);
    iq = fminf(fmaxf(iq, -2147483648.0f), 2147483648.0f);
    float e = __expf(-iq * 7.450580596923828125e-9f);
    float s = __builtin_amdgcn_rcpf(1.0f + e);
    float q31 = floorf(s * 2147483648.0f + 0.5f);
    float q15 = floorf(q31 * 1.52587890625e-5f + 0.5f);
    return q15 * 3.0517578125e-5f;
}

__device__ __forceinline__ float qtanh_dev(float x) {
    float iq = floorf(x * 134217728.0f + 0.5f);
    iq = fminf(fmaxf(iq, -2147483648.0f), 2147483648.0f);
    float z = iq * 7.450580596923828125e-9f;
    float e = __expf(2.0f * z);
    float t = 1.0f - 2.0f * __builtin_amdgcn_rcpf(e + 1.0f);
    float q31 = floorf(t * 2147483648.0f + 0.5f);
    float q15 = floorf(q31 * 1.52587890625e-5f + 0.5f);
    return q15 * 3.0517578125e-5f;
}

__device__ __forceinline__ void dma16(const void* g, void* l) {
    __builtin_amdgcn_global_load_lds(
        (const __attribute__((address_space(1))) unsigned int*)g,
        (__attribute__((address_space(3))) unsigned int*)l, 16, 0, 0);
}

__device__ __forceinline__ void split2(float a, float b, unsigned& hi, unsigned& lo) {
    unsigned ua = __float_as_uint(a); ua += 0x7fffu + ((ua >> 16) & 1u);
    unsigned ub = __float_as_uint(b); ub += 0x7fffu + ((ub >> 16) & 1u);
    hi = (ua >> 16) | (ub & 0xffff0000u);
    float ra = a - __uint_as_float(ua & 0xffff0000u);
    float rb = b - __uint_as_float(ub & 0xffff0000u);
    unsigned va = __float_as_uint(ra); va += 0x7fffu + ((va >> 16) & 1u);
    unsigned vb = __float_as_uint(rb); vb += 0x7fffu + ((vb >> 16) & 1u);
    lo = (va >> 16) | (vb & 0xffff0000u);
}

} // namespace

// ---------------- pre-pass: W-only LDS-tile-transpose fp32 -> f16 chunks ---
// 96 W groups x 2 K-halves = 192 blocks. Same swizzle algebra as before.
__global__ __launch_bounds__(256) void cvt_w_f16(
    const float* __restrict__ wih, const float* __restrict__ whh,
    _Float16* __restrict__ ws)
{
    __shared__ __align__(16) _Float16 lt[8192];   // 16 KB

    const int b2  = blockIdx.x;            // 0..191
    const int w   = b2 >> 1;               // 0..95
    const int kha = b2 & 1;
    const int tid = threadIdx.x;

    const int g = w >> 4, N32 = w & 15;
    const int rowLocal = (g % 3) * 512 + N32 * 32;
    const float* src = (g < 3 ? wih : whh)
                     + (size_t)rowLocal * 512u + (size_t)kha * 256u;
    const unsigned chbase = WCH0 + (unsigned)((g * 16 + N32) * 32);

    // Phase 1: 8 reps x 256 threads covering 32 rows x 64 float4s
#pragma unroll
    for (int rep = 0; rep < 8; ++rep) {
        const int idx = rep * 256 + tid;       // 0..2047
        const int row = idx >> 6;              // 0..31
        const int q   = idx & 63;              // local float4 col
        const float4 v = *(const float4*)(src + (size_t)row * 512 + q * 4);
        const int K16l = q >> 2;               // 0..15
        const int kh   = (q >> 1) & 1;
        const int half = (q & 1) * 4;
        const int rsw  = (row + (q >> 1)) & 31;
        f16x4 o;
        o[0] = (_Float16)v.x; o[1] = (_Float16)v.y;
        o[2] = (_Float16)v.z; o[3] = (_Float16)v.w;
        *(f16x4*)&lt[K16l * 512 + kh * 256 + rsw * 8 + half] = o;
    }
    __syncthreads();

    // Phase 2: wave w writes chunks K16l = wv*4 .. wv*4+3
    const int wv = tid >> 6, lane = tid & 63;
    const int kh = lane >> 5, row = lane & 31;
#pragma unroll
    for (int cc = 0; cc < 4; ++cc) {
        const int K16l = wv * 4 + cc;
        const int rsw  = (row + 2 * K16l + kh) & 31;
        const f16x8 o = *(const f16x8*)&lt[K16l * 512 + kh * 256 + rsw * 8];
        *(f16x8*)(ws + (size_t)(chbase + (unsigned)(kha * 16 + K16l)) * 512u
                      + lane * 8) = o;
    }
}

// ---------------- main: R13 structure + fused in-kernel A conversion -------
__global__ __launch_bounds__(256, 4) void qgru_f16_fuseA(
    const float* __restrict__ x, const float* __restrict__ hid,
    const _Float16* __restrict__ ws,
    const float* __restrict__ bih, const float* __restrict__ bhh,
    float* __restrict__ out)
{
    __shared__ __align__(16) _Float16 lds[16384];   // 32 KB (2 slabs x 16 KB)

    const int t = threadIdx.x, lane = t & 63, wid = t >> 6;
    const int mt = wid >> 1, nt = wid & 1;
    const int m0 = blockIdx.x * BM, n0 = blockIdx.y * BN;

    // W staging: 12 chunks/step, 3 dma16 per wave (same mapping as R13)
    unsigned goffW[3];
    int      ldstW[3];
#pragma unroll
    for (int c = 0; c < 3; ++c) {
        const int wp = wid * 3 + c;        // 0..11
        const int g = wp >> 1, ntc = wp & 1;
        const unsigned ch = WCH0 + (unsigned)((g * 16 + (n0 >> 5) + ntc) * 32);
        goffW[c] = ch * 1024u + (unsigned)lane * 16u;
        ldstW[c] = 2048 + wp * 512;
    }

    // A staging: wave wid covers (arr = wid>>1, mtc = wid&1): 32 rows x 16 k
    // per step, as 2 coalesced float4 loads + cvt + 2 ds_write_b64 per lane.
    // LDS chunk layout == ws chunk layout: pos(row,k)=(k>>3)*256+row*8+(k&7).
    const int arr = wid >> 1, mtc = wid & 1;
    const float* srcA = (arr ? hid : x) + (size_t)(m0 + mtc * 32) * 512u;
    const int r32a = lane >> 2, sega = lane & 3;          // 16 rows x 4 segs
    const size_t ga0 = (size_t)r32a * 512u + (size_t)(sega * 4);
    const size_t ga1 = ga0 + 16u * 512u;                  // rows 16..31
    const int aoff0 = wid * 512 + (sega >> 1) * 256 + r32a * 8 + (sega & 1) * 4;
    const int aoff1 = aoff0 + 128;                        // +16 rows * 8

    f32x16 acc[6];
#pragma unroll
    for (int g = 0; g < 6; ++g)
#pragma unroll
        for (int i = 0; i < 16; ++i) acc[g][i] = 0.0f;

    const char* wsb = (const char*)ws;
    const int lr = lane & 31, lk8 = (lane >> 5) * 8;

    // ---- prologue: stage step 0, issue A loads for step 1 ----
    float4 vA0 = *(const float4*)(srcA + ga0);
    float4 vA1 = *(const float4*)(srcA + ga1);
#pragma unroll
    for (int c = 0; c < 3; ++c)
        dma16(wsb + goffW[c], &lds[ldstW[c]]);
    {
        f16x4 o0, o1;
        o0[0] = (_Float16)vA0.x; o0[1] = (_Float16)vA0.y;
        o0[2] = (_Float16)vA0.z; o0[3] = (_Float16)vA0.w;
        o1[0] = (_Float16)vA1.x; o1[1] = (_Float16)vA1.y;
        o1[2] = (_Float16)vA1.z; o1[3] = (_Float16)vA1.w;
        *(f16x4*)&lds[aoff0] = o0;
        *(f16x4*)&lds[aoff1] = o1;
    }
    vA0 = *(const float4*)(srcA + 16 + ga0);   // k-slice 1
    vA1 = *(const float4*)(srcA + 16 + ga1);

    for (int step = 0; step < 32; ++step) {
        __syncthreads();   // drains vmcnt+lgkmcnt for all waves: slab[cur] ready

        if (step + 1 < 32) {
            const unsigned kb = (unsigned)(step + 1) * 1024u;
            const int nb = ((step + 1) & 1) * 8192;
#pragma unroll
            for (int c = 0; c < 3; ++c)
                dma16(wsb + goffW[c] + kb, &lds[nb + ldstW[c]]);
            f16x4 o0, o1;
            o0[0] = (_Float16)vA0.x; o0[1] = (_Float16)vA0.y;
            o0[2] = (_Float16)vA0.z; o0[3] = (_Float16)vA0.w;
            o1[0] = (_Float16)vA1.x; o1[1] = (_Float16)vA1.y;
            o1[2] = (_Float16)vA1.z; o1[3] = (_Float16)vA1.w;
            *(f16x4*)&lds[nb + aoff0] = o0;
            *(f16x4*)&lds[nb + aoff1] = o1;
            if (step + 2 < 32) {
                const size_t ko = (size_t)(step + 2) * 16u;
                vA0 = *(const float4*)(srcA + ko + ga0);
                vA1 = *(const float4*)(srcA + ko + ga1);
            }
        }

        const int cb = (step & 1) * 8192;
        const int lfo = cb + lk8 * 32 + lr * 8;
        const f16x8 ax = *(const f16x8*)&lds[lfo + (0 + mt) * 512];
        const f16x8 ah = *(const f16x8*)&lds[lfo + (2 + mt) * 512];
#pragma unroll
        for (int g = 0; g < 6; ++g) {
            const f16x8 b = *(const f16x8*)&lds[lfo + 2048 + (g * 2 + nt) * 512];
            acc[g] = __builtin_amdgcn_mfma_f32_32x32x16_f16(
                         g < 3 ? ax : ah, b, acc[g], 0, 0, 0);
        }
    }

    constexpr float S14 = 16384.0f,     I14 = 1.0f / 16384.0f;
    constexpr float S15 = 32768.0f,     I15 = 1.0f / 32768.0f;
    constexpr float S27 = 134217728.0f, I27 = 1.0f / 134217728.0f;

    const int lh = lane >> 5, l32 = lane & 31;
    const int n = n0 + nt * 32 + l32;
    const float br = bih[n], bi = bih[n + 512], bn = bih[n + 1024];
    const float cr = bhh[n], ci = bhh[n + 512], cn = bhh[n + 1024];

#pragma unroll
    for (int r = 0; r < 16; ++r) {
        const int row = (r & 3) + 8 * (r >> 2) + 4 * lh;
        const int m   = m0 + mt * 32 + row;
        const float hv = hid[(size_t)m * Hsz + n];

        float gir = qround(acc[0][r] + br, S14, I14);
        float gii = qround(acc[1][r] + bi, S14, I14);
        float gin = qround(acc[2][r] + bn, S14, I14);
        float ghr = qround(acc[3][r] + cr, S14, I14);
        float ghi = qround(acc[4][r] + ci, S14, I14);
        float ghn = qround(acc[5][r] + cn, S14, I14);
        float resetg = qsigmoid_dev(gir + ghr);
        float inputg = qsigmoid_dev(gii + ghi);
        float hn  = qround(ghn, S27, I27);
        float rh  = qround(resetg * hn, S15, I15);
        float newg = qtanh_dev(rh + gin);
        float nh  = qround(hv, S15, I15);
        out[(size_t)m * Hsz + n] = newg + inputg * (nh - newg);
    }
}

// ---------------- fallback: bf16x3 (used only if ws too small) -------------
__global__ __launch_bounds__(256, 2) void qgru_mfma_bf16x3(
    const float* __restrict__ x, const float* __restrict__ hid,
    const float* __restrict__ wih, const float* __restrict__ whh,
    const float* __restrict__ bih, const float* __restrict__ bhh,
    float* __restrict__ out)
{
    __shared__ __align__(16) unsigned short lds[16384];

    const int t = threadIdx.x, lane = t & 63, wid = t >> 6;
    const int mt = wid >> 1, nt = wid & 1;
    const int m0 = blockIdx.x * BM, n0 = blockIdx.y * BN;
    const int s_r = t >> 2, s_k = (t & 3) << 2;
    const int s_kh = s_k >> 3, s_j = s_k & 7, s_rt = s_r >> 5, s_r32 = s_r & 31;

    const float* gA[2];
    gA[0] = x   + (size_t)(m0 + s_r) * Ksz + s_k;
    gA[1] = hid + (size_t)(m0 + s_r) * Ksz + s_k;
    const float* gW[6];
#pragma unroll
    for (int g = 0; g < 3; ++g) {
        gW[g]     = wih + (size_t)(g * Hsz + n0 + s_r) * Ksz + s_k;
        gW[g + 3] = whh + (size_t)(g * Hsz + n0 + s_r) * Ksz + s_k;
    }
    const int lh = lane >> 5, l32 = lane & 31;

    f32x16 acc[6];
#pragma unroll
    for (int g = 0; g < 6; ++g)
#pragma unroll
        for (int i = 0; i < 16; ++i) acc[g][i] = 0.0f;

    float4 vA[2], vW[6];
#pragma unroll
    for (int tt = 0; tt < 2; ++tt) vA[tt] = *(const float4*)gA[tt];
#pragma unroll
    for (int g = 0; g < 6; ++g)    vW[g]  = *(const float4*)gW[g];

    for (int k0 = 0; k0 < Ksz; k0 += 16) {
        __syncthreads();
#pragma unroll
        for (int tt = 0; tt < 2; ++tt) {
            unsigned h0, h1, l0, l1;
            split2(vA[tt].x, vA[tt].y, h0, l0);
            split2(vA[tt].z, vA[tt].w, h1, l1);
            unsigned bH = ((((tt*2+0)*2+s_rt)*2+s_kh)*32+s_r32)*8 + s_j;
            unsigned bL = ((((tt*2+1)*2+s_rt)*2+s_kh)*32+s_r32)*8 + s_j;
            *reinterpret_cast<uint2*>(&lds[bH]) = make_uint2(h0, h1);
            *reinterpret_cast<uint2*>(&lds[bL]) = make_uint2(l0, l1);
        }
#pragma unroll
        for (int g = 0; g < 6; ++g) {
            unsigned h0, h1, l0, l1;
            split2(vW[g].x, vW[g].y, h0, l0);
            split2(vW[g].z, vW[g].w, h1, l1);
            unsigned bH = 4096u + ((((g*2+0)*2+s_rt)*2+s_kh)*32+s_r32)*8 + s_j;
            unsigned bL = 4096u + ((((g*2+1)*2+s_rt)*2+s_kh)*32+s_r32)*8 + s_j;
            *reinterpret_cast<uint2*>(&lds[bH]) = make_uint2(h0, h1);
            *reinterpret_cast<uint2*>(&lds[bL]) = make_uint2(l0, l1);
        }
        __syncthreads();
        const int kn = (k0 + 16 < Ksz) ? (k0 + 16) : 0;
#pragma unroll
        for (int tt = 0; tt < 2; ++tt) vA[tt] = *(const float4*)(gA[tt] + kn);
#pragma unroll
        for (int g = 0; g < 6; ++g)    vW[g]  = *(const float4*)(gW[g] + kn);

        const bf16x8 ax_hi = *reinterpret_cast<const bf16x8*>(&lds[((((0)*2+mt)*2+lh)*32+l32)*8]);
        const bf16x8 ax_lo = *reinterpret_cast<const bf16x8*>(&lds[((((1)*2+mt)*2+lh)*32+l32)*8]);
        const bf16x8 ah_hi = *reinterpret_cast<const bf16x8*>(&lds[((((2)*2+mt)*2+lh)*32+l32)*8]);
        const bf16x8 ah_lo = *reinterpret_cast<const bf16x8*>(&lds[((((3)*2+mt)*2+lh)*32+l32)*8]);
#pragma unroll
        for (int g = 0; g < 6; ++g) {
            const bf16x8 b_hi = *reinterpret_cast<const bf16x8*>(&lds[4096u + ((((g*2+0)*2+nt)*2+lh)*32+l32)*8]);
            const bf16x8 b_lo = *reinterpret_cast<const bf16x8*>(&lds[4096u + ((((g*2+1)*2+nt)*2+lh)*32+l32)*8]);
            const bf16x8 a_hi = (g < 3) ? ax_hi : ah_hi;
            const bf16x8 a_lo = (g < 3) ? ax_lo : ah_lo;
            acc[g] = __builtin_amdgcn_mfma_f32_32x32x16_bf16(a_hi, b_hi, acc[g], 0, 0, 0);
            acc[g] = __builtin_amdgcn_mfma_f32_32x32x16_bf16(a_hi, b_lo, acc[g], 0, 0, 0);
            acc[g] = __builtin_amdgcn_mfma_f32_32x32x16_bf16(a_lo, b_hi, acc[g], 0, 0, 0);
        }
    }

    constexpr float S14 = 16384.0f,     I14 = 1.0f / 16384.0f;
    constexpr float S15 = 32768.0f,     I15 = 1.0f / 32768.0f;
    constexpr float S27 = 134217728.0f, I27 = 1.0f / 134217728.0f;
    const int n = n0 + nt * 32 + l32;
    const float br = bih[n], bi = bih[n + 512], bn = bih[n + 1024];
    const float cr = bhh[n], ci = bhh[n + 512], cn = bhh[n + 1024];
#pragma unroll
    for (int r = 0; r < 16; ++r) {
        const int row = (r & 3) + 8 * (r >> 2) + 4 * lh;
        const int m   = m0 + mt * 32 + row;
        const float hv = hid[(size_t)m * Hsz + n];
        float gir = qround(acc[0][r] + br, S14, I14);
        float gii = qround(acc[1][r] + bi, S14, I14);
        float gin = qround(acc[2][r] + bn, S14, I14);
        float ghr = qround(acc[3][r] + cr, S14, I14);
        float ghi = qround(acc[4][r] + ci, S14, I14);
        float ghn = qround(acc[5][r] + cn, S14, I14);
        float resetg = qsigmoid_dev(gir + ghr);
        float inputg = qsigmoid_dev(gii + ghi);
        float hn  = qround(ghn, S27, I27);
        float rh  = qround(resetg * hn, S15, I15);
        float newg = qtanh_dev(rh + gin);
        float nh  = qround(hv, S15, I15);
        out[(size_t)m * Hsz + n] = newg + inputg * (nh - newg);
    }
}

extern "C" void kernel_launch(void* const* d_in, const int* in_sizes, int n_in,
                              void* d_out, int out_size, void* d_ws, size_t ws_size,
                              hipStream_t stream) {
    const float* x   = (const float*)d_in[0];
    const float* hid = (const float*)d_in[1];
    const float* wih = (const float*)d_in[2];
    const float* whh = (const float*)d_in[3];
    const float* bih = (const float*)d_in[4];
    const float* bhh = (const float*)d_in[5];
    float* out = (float*)d_out;
    dim3 grid(Bsz / BM, Hsz / BN);   // 128 x 8 = 1024 blocks = 4/CU

    if (ws_size >= WS_NEED) {
        cvt_w_f16<<<192, 256, 0, stream>>>(wih, whh, (_Float16*)d_ws);
        qgru_f16_fuseA<<<grid, dim3(256), 0, stream>>>(
            x, hid, (const _Float16*)d_ws, bih, bhh, out);
    } else {
        qgru_mfma_bf16x3<<<grid, dim3(256), 0, stream>>>(
            x, hid, wih, whh, bih, bhh, out);
    }
}

// Round 9
// 127.953 us; speedup vs baseline: 1.0428x; 1.0428x over previous
//
#include <hip/hip_runtime.h>
#include <math.h>

// QGRUCell — Round 15: consolidation. qgru = R13 verbatim (best measured,
// 43.0us, KT=16, 32KB dbuf, 4 blocks/CU). R14's fused-A regressed (58us,
// 1M bank conflicts + 8x L2 request rate from strided f32 loads) — reverted.
// cvt: split groups over K-QUARTERS (608 groups x 4 = 2432 blocks, 8KB LDS,
// 8 blocks/CU residency) to fix the 4.75-blocks/CU quantization tail that
// held cvt at 4.1 TB/s vs the 6.2 floor. Same swizzle algebra (block-local
// consistent), ws bytes bit-identical.
// ws: 512-f16 chunks, A: arr*8192+M32*32+K16, W: 16384+(g*16+N32)*32+K16;
// chunk pos(row,k)=(k>>3&1)*256+row*8+(k&7).

typedef _Float16 f16x8  __attribute__((ext_vector_type(8)));
typedef _Float16 f16x4  __attribute__((ext_vector_type(4)));
typedef __bf16   bf16x8 __attribute__((ext_vector_type(8)));
typedef float    f32x16 __attribute__((ext_vector_type(16)));

namespace {

constexpr int Bsz = 8192, Ksz = 512, Hsz = 512;
constexpr int BM = 64, BN = 64;

constexpr unsigned WCH0    = 16384u;
constexpr unsigned NCHUNK  = 16384u + 3072u;          // 19456
constexpr unsigned WS_F16  = NCHUNK * 512u;           // 9,961,472 f16
constexpr size_t   WS_NEED = (size_t)WS_F16 * 2;      // 19,922,944 B

__device__ __forceinline__ float qround(float x, float s, float invs) {
    return floorf(x * s + 0.5f) * invs;
}

__device__ __forceinline__ float qsigmoid_dev(float x) {
    float iq = floorf(x * 134217728.0f + 0.5f);
    iq = fminf(fmaxf(iq, -2147483648.0f), 2147483648.0f);
    float e = __expf(-iq * 7.450580596923828125e-9f);
    float s = __builtin_amdgcn_rcpf(1.0f + e);
    float q31 = floorf(s * 2147483648.0f + 0.5f);
    float q15 = floorf(q31 * 1.52587890625e-5f + 0.5f);
    return q15 * 3.0517578125e-5f;
}

__device__ __forceinline__ float qtanh_dev(float x) {
    float iq = floorf(x * 134217728.0f + 0.5f);
    iq = fminf(fmaxf(iq, -2147483648.0f), 2147483648.0f);
    float z = iq * 7.450580596923828125e-9f;
    float e = __expf(2.0f * z);
    float t = 1.0f - 2.0f * __builtin_amdgcn_rcpf(e + 1.0f);
    float q31 = floorf(t * 2147483648.0f + 0.5f);
    float q15 = floorf(q31 * 1.52587890625e-5f + 0.5f);
    return q15 * 3.0517578125e-5f;
}

__device__ __forceinline__ void dma16(const void* g, void* l) {
    __builtin_amdgcn_global_load_lds(
        (const __attribute__((address_space(1))) unsigned int*)g,
        (__attribute__((address_space(3))) unsigned int*)l, 16, 0, 0);
}

__device__ __forceinline__ void split2(float a, float b, unsigned& hi, unsigned& lo) {
    unsigned ua = __float_as_uint(a); ua += 0x7fffu + ((ua >> 16) & 1u);
    unsigned ub = __float_as_uint(b); ub += 0x7fffu + ((ub >> 16) & 1u);
    hi = (ua >> 16) | (ub & 0xffff0000u);
    float ra = a - __uint_as_float(ua & 0xffff0000u);
    float rb = b - __uint_as_float(ub & 0xffff0000u);
    unsigned va = __float_as_uint(ra); va += 0x7fffu + ((va >> 16) & 1u);
    unsigned vb = __float_as_uint(rb); vb += 0x7fffu + ((vb >> 16) & 1u);
    lo = (va >> 16) | (vb & 0xffff0000u);
}

} // namespace

// ---------------- pre-pass: LDS-tile-transpose fp32 -> f16 chunks ----------
// K-quarter split: block b4 = 4*group + kq handles 32 rows x 128 cols.
// 608 groups x 4 = 2432 blocks, 8KB LDS => 8 blocks/CU residency.
__global__ __launch_bounds__(256) void cvt_lds_f16(
    const float* __restrict__ x, const float* __restrict__ h,
    const float* __restrict__ wih, const float* __restrict__ whh,
    _Float16* __restrict__ ws)
{
    __shared__ __align__(16) _Float16 lt[4096];   // 8 KB

    const int b4  = blockIdx.x;
    const int b   = b4 >> 2;
    const int kq  = b4 & 3;
    const int tid = threadIdx.x;

    const float* src;      // base of the 32-row group (row-major, stride 512)
    unsigned chbase;       // first chunk index of this group
    if (b < 512) {                         // A: x (arr0), h (arr1)
        const int arr = b >> 8, M32 = b & 255;
        src = (arr ? h : x) + (size_t)M32 * 32u * 512u;
        chbase = (unsigned)arr * 8192u + (unsigned)M32 * 32u;
    } else {                               // W: gate g, col-group N32
        const int w = b - 512;             // 0..95
        const int g = w >> 4, N32 = w & 15;
        const int rowLocal = (g % 3) * 512 + N32 * 32;
        src = (g < 3 ? wih : whh) + (size_t)rowLocal * 512u;
        chbase = WCH0 + (unsigned)((g * 16 + N32) * 32);
    }
    src += kq * 128;                       // K-quarter column offset

    // Phase 1: 4 reps x 256 threads covering 32 rows x 32 float4s
#pragma unroll
    for (int rep = 0; rep < 4; ++rep) {
        const int idx = rep * 256 + tid;       // 0..1023
        const int row = idx >> 5;              // 0..31
        const int q   = idx & 31;              // local float4 col
        const float4 v = *(const float4*)(src + (size_t)row * 512 + q * 4);
        const int K16l = q >> 2;               // 0..7
        const int kh   = (q >> 1) & 1;
        const int half = (q & 1) * 4;
        const int rsw  = (row + (q >> 1)) & 31;
        f16x4 o;
        o[0] = (_Float16)v.x; o[1] = (_Float16)v.y;
        o[2] = (_Float16)v.z; o[3] = (_Float16)v.w;
        *(f16x4*)&lt[K16l * 512 + kh * 256 + rsw * 8 + half] = o;
    }
    __syncthreads();

    // Phase 2: wave wv writes chunks K16l = wv*2, wv*2+1
    const int wv = tid >> 6, lane = tid & 63;
    const int kh = lane >> 5, row = lane & 31;
#pragma unroll
    for (int cc = 0; cc < 2; ++cc) {
        const int K16l = wv * 2 + cc;
        const int rsw  = (row + 2 * K16l + kh) & 31;
        const f16x8 o = *(const f16x8*)&lt[K16l * 512 + kh * 256 + rsw * 8];
        *(f16x8*)(ws + (size_t)(chbase + (unsigned)(kq * 8 + K16l)) * 512u
                      + lane * 8) = o;
    }
}

// ---------------- main: R13 verbatim (KT=16, 32KB LDS, 4 blocks/CU) --------
__global__ __launch_bounds__(256, 4) void qgru_f16_occ(
    const _Float16* __restrict__ ws, const float* __restrict__ hid,
    const float* __restrict__ bih, const float* __restrict__ bhh,
    float* __restrict__ out)
{
    __shared__ __align__(16) _Float16 lds[16384];   // 32 KB (2 slabs x 16 KB)

    const int t = threadIdx.x, lane = t & 63, wid = t >> 6;
    const int mt = wid >> 1, nt = wid & 1;
    const int m0 = blockIdx.x * BM, n0 = blockIdx.y * BN;

    // 16 chunks per step (one K16 slice): idx 0..3 = A (arr, mtc),
    // idx 4..15 = W (g, ntc). Wave wid stages idx = wid*4 .. wid*4+3.
    unsigned goff[4];
    int      ldst[4];
#pragma unroll
    for (int c = 0; c < 4; ++c) {
        const int idx = wid * 4 + c;
        unsigned ch; int lo;
        if (idx < 4) {
            const int arr = idx >> 1, mtc = idx & 1;
            ch = (unsigned)arr * 8192u + (unsigned)((m0 >> 5) + mtc) * 32u;
            lo = idx * 512;
        } else {
            const int w = idx - 4, g = w >> 1, ntc = w & 1;
            ch = WCH0 + (unsigned)((g * 16 + (n0 >> 5) + ntc) * 32);
            lo = 2048 + w * 512;
        }
        goff[c] = ch * 1024u + (unsigned)lane * 16u;
        ldst[c] = lo;
    }

    f32x16 acc[6];
#pragma unroll
    for (int g = 0; g < 6; ++g)
#pragma unroll
        for (int i = 0; i < 16; ++i) acc[g][i] = 0.0f;

    const char* wsb = (const char*)ws;
    const int lr = lane & 31, lk8 = (lane >> 5) * 8;

#pragma unroll
    for (int c = 0; c < 4; ++c)
        dma16(wsb + goff[c], &lds[ldst[c]]);

    for (int step = 0; step < 32; ++step) {
        __syncthreads();                       // implicit vmcnt(0) drain

        if (step + 1 < 32) {
            const unsigned kb = (unsigned)(step + 1) * 1024u;
            const int nb = ((step + 1) & 1) * 8192;
#pragma unroll
            for (int c = 0; c < 4; ++c)
                dma16(wsb + goff[c] + kb, &lds[nb + ldst[c]]);
        }

        const int cb = (step & 1) * 8192;
        const int lfo = cb + lk8 * 32 + lr * 8;
        const f16x8 ax = *(const f16x8*)&lds[lfo + (0 + mt) * 512];
        const f16x8 ah = *(const f16x8*)&lds[lfo + (2 + mt) * 512];
#pragma unroll
        for (int g = 0; g < 6; ++g) {
            const f16x8 b = *(const f16x8*)&lds[lfo + 2048 + (g * 2 + nt) * 512];
            acc[g] = __builtin_amdgcn_mfma_f32_32x32x16_f16(
                         g < 3 ? ax : ah, b, acc[g], 0, 0, 0);
        }
    }

    constexpr float S14 = 16384.0f,     I14 = 1.0f / 16384.0f;
    constexpr float S15 = 32768.0f,     I15 = 1.0f / 32768.0f;
    constexpr float S27 = 134217728.0f, I27 = 1.0f / 134217728.0f;

    const int lh = lane >> 5, l32 = lane & 31;
    const int n = n0 + nt * 32 + l32;
    const float br = bih[n], bi = bih[n + 512], bn = bih[n + 1024];
    const float cr = bhh[n], ci = bhh[n + 512], cn = bhh[n + 1024];

#pragma unroll
    for (int r = 0; r < 16; ++r) {
        const int row = (r & 3) + 8 * (r >> 2) + 4 * lh;
        const int m   = m0 + mt * 32 + row;
        const float hv = hid[(size_t)m * Hsz + n];

        float gir = qround(acc[0][r] + br, S14, I14);
        float gii = qround(acc[1][r] + bi, S14, I14);
        float gin = qround(acc[2][r] + bn, S14, I14);
        float ghr = qround(acc[3][r] + cr, S14, I14);
        float ghi = qround(acc[4][r] + ci, S14, I14);
        float ghn = qround(acc[5][r] + cn, S14, I14);
        float resetg = qsigmoid_dev(gir + ghr);
        float inputg = qsigmoid_dev(gii + ghi);
        float hn  = qround(ghn, S27, I27);
        float rh  = qround(resetg * hn, S15, I15);
        float newg = qtanh_dev(rh + gin);
        float nh  = qround(hv, S15, I15);
        out[(size_t)m * Hsz + n] = newg + inputg * (nh - newg);
    }
}

// ---------------- fallback: bf16x3 (used only if ws too small) -------------
__global__ __launch_bounds__(256, 2) void qgru_mfma_bf16x3(
    const float* __restrict__ x, const float* __restrict__ hid,
    const float* __restrict__ wih, const float* __restrict__ whh,
    const float* __restrict__ bih, const float* __restrict__ bhh,
    float* __restrict__ out)
{
    __shared__ __align__(16) unsigned short lds[16384];

    const int t = threadIdx.x, lane = t & 63, wid = t >> 6;
    const int mt = wid >> 1, nt = wid & 1;
    const int m0 = blockIdx.x * BM, n0 = blockIdx.y * BN;
    const int s_r = t >> 2, s_k = (t & 3) << 2;
    const int s_kh = s_k >> 3, s_j = s_k & 7, s_rt = s_r >> 5, s_r32 = s_r & 31;

    const float* gA[2];
    gA[0] = x   + (size_t)(m0 + s_r) * Ksz + s_k;
    gA[1] = hid + (size_t)(m0 + s_r) * Ksz + s_k;
    const float* gW[6];
#pragma unroll
    for (int g = 0; g < 3; ++g) {
        gW[g]     = wih + (size_t)(g * Hsz + n0 + s_r) * Ksz + s_k;
        gW[g + 3] = whh + (size_t)(g * Hsz + n0 + s_r) * Ksz + s_k;
    }
    const int lh = lane >> 5, l32 = lane & 31;

    f32x16 acc[6];
#pragma unroll
    for (int g = 0; g < 6; ++g)
#pragma unroll
        for (int i = 0; i < 16; ++i) acc[g][i] = 0.0f;

    float4 vA[2], vW[6];
#pragma unroll
    for (int tt = 0; tt < 2; ++tt) vA[tt] = *(const float4*)gA[tt];
#pragma unroll
    for (int g = 0; g < 6; ++g)    vW[g]  = *(const float4*)gW[g];

    for (int k0 = 0; k0 < Ksz; k0 += 16) {
        __syncthreads();
#pragma unroll
        for (int tt = 0; tt < 2; ++tt) {
            unsigned h0, h1, l0, l1;
            split2(vA[tt].x, vA[tt].y, h0, l0);
            split2(vA[tt].z, vA[tt].w, h1, l1);
            unsigned bH = ((((tt*2+0)*2+s_rt)*2+s_kh)*32+s_r32)*8 + s_j;
            unsigned bL = ((((tt*2+1)*2+s_rt)*2+s_kh)*32+s_r32)*8 + s_j;
            *reinterpret_cast<uint2*>(&lds[bH]) = make_uint2(h0, h1);
            *reinterpret_cast<uint2*>(&lds[bL]) = make_uint2(l0, l1);
        }
#pragma unroll
        for (int g = 0; g < 6; ++g) {
            unsigned h0, h1, l0, l1;
            split2(vW[g].x, vW[g].y, h0, l0);
            split2(vW[g].z, vW[g].w, h1, l1);
            unsigned bH = 4096u + ((((g*2+0)*2+s_rt)*2+s_kh)*32+s_r32)*8 + s_j;
            unsigned bL = 4096u + ((((g*2+1)*2+s_rt)*2+s_kh)*32+s_r32)*8 + s_j;
            *reinterpret_cast<uint2*>(&lds[bH]) = make_uint2(h0, h1);
            *reinterpret_cast<uint2*>(&lds[bL]) = make_uint2(l0, l1);
        }
        __syncthreads();
        const int kn = (k0 + 16 < Ksz) ? (k0 + 16) : 0;
#pragma unroll
        for (int tt = 0; tt < 2; ++tt) vA[tt] = *(const float4*)(gA[tt] + kn);
#pragma unroll
        for (int g = 0; g < 6; ++g)    vW[g]  = *(const float4*)(gW[g] + kn);

        const bf16x8 ax_hi = *reinterpret_cast<const bf16x8*>(&lds[((((0)*2+mt)*2+lh)*32+l32)*8]);
        const bf16x8 ax_lo = *reinterpret_cast<const bf16x8*>(&lds[((((1)*2+mt)*2+lh)*32+l32)*8]);
        const bf16x8 ah_hi = *reinterpret_cast<const bf16x8*>(&lds[((((2)*2+mt)*2+lh)*32+l32)*8]);
        const bf16x8 ah_lo = *reinterpret_cast<const bf16x8*>(&lds[((((3)*2+mt)*2+lh)*32+l32)*8]);
#pragma unroll
        for (int g = 0; g < 6; ++g) {
            const bf16x8 b_hi = *reinterpret_cast<const bf16x8*>(&lds[4096u + ((((g*2+0)*2+nt)*2+lh)*32+l32)*8]);
            const bf16x8 b_lo = *reinterpret_cast<const bf16x8*>(&lds[4096u + ((((g*2+1)*2+nt)*2+lh)*32+l32)*8]);
            const bf16x8 a_hi = (g < 3) ? ax_hi : ah_hi;
            const bf16x8 a_lo = (g < 3) ? ax_lo : ah_lo;
            acc[g] = __builtin_amdgcn_mfma_f32_32x32x16_bf16(a_hi, b_hi, acc[g], 0, 0, 0);
            acc[g] = __builtin_amdgcn_mfma_f32_32x32x16_bf16(a_hi, b_lo, acc[g], 0, 0, 0);
            acc[g] = __builtin_amdgcn_mfma_f32_32x32x16_bf16(a_lo, b_hi, acc[g], 0, 0, 0);
        }
    }

    constexpr float S14 = 16384.0f,     I14 = 1.0f / 16384.0f;
    constexpr float S15 = 32768.0f,     I15 = 1.0f / 32768.0f;
    constexpr float S27 = 134217728.0f, I27 = 1.0f / 134217728.0f;
    const int n = n0 + nt * 32 + l32;
    const float br = bih[n], bi = bih[n + 512], bn = bih[n + 1024];
    const float cr = bhh[n], ci = bhh[n + 512], cn = bhh[n + 1024];
#pragma unroll
    for (int r = 0; r < 16; ++r) {
        const int row = (r & 3) + 8 * (r >> 2) + 4 * lh;
        const int m   = m0 + mt * 32 + row;
        const float hv = hid[(size_t)m * Hsz + n];
        float gir = qround(acc[0][r] + br, S14, I14);
        float gii = qround(acc[1][r] + bi, S14, I14);
        float gin = qround(acc[2][r] + bn, S14, I14);
        float ghr = qround(acc[3][r] + cr, S14, I14);
        float ghi = qround(acc[4][r] + ci, S14, I14);
        float ghn = qround(acc[5][r] + cn, S14, I14);
        float resetg = qsigmoid_dev(gir + ghr);
        float inputg = qsigmoid_dev(gii + ghi);
        float hn  = qround(ghn, S27, I27);
        float rh  = qround(resetg * hn, S15, I15);
        float newg = qtanh_dev(rh + gin);
        float nh  = qround(hv, S15, I15);
        out[(size_t)m * Hsz + n] = newg + inputg * (nh - newg);
    }
}

extern "C" void kernel_launch(void* const* d_in, const int* in_sizes, int n_in,
                              void* d_out, int out_size, void* d_ws, size_t ws_size,
                              hipStream_t stream) {
    const float* x   = (const float*)d_in[0];
    const float* hid = (const float*)d_in[1];
    const float* wih = (const float*)d_in[2];
    const float* whh = (const float*)d_in[3];
    const float* bih = (const float*)d_in[4];
    const float* bhh = (const float*)d_in[5];
    float* out = (float*)d_out;
    dim3 grid(Bsz / BM, Hsz / BN);   // 128 x 8 = 1024 blocks = 4/CU

    if (ws_size >= WS_NEED) {
        cvt_lds_f16<<<2432, 256, 0, stream>>>(
            x, hid, wih, whh, (_Float16*)d_ws);
        qgru_f16_occ<<<grid, dim3(256), 0, stream>>>(
            (const _Float16*)d_ws, hid, bih, bhh, out);
    } else {
        qgru_mfma_bf16x3<<<grid, dim3(256), 0, stream>>>(
            x, hid, wih, whh, bih, bhh, out);
    }
}